// Round 5
// baseline (1188.483 us; speedup 1.0000x reference)
//
#include <hip/hip_runtime.h>

#define N_NODES 100000
#define N_EDGES 1600000
#define D 64
#define EPS 1e-5f

// ---------------- workspace layout (byte offsets, 16B-aligned) --------------
// flag    @ 0         (256)
// deg     @ 256       (N*4)        -> 400256
// dinv    @ 400256    (N*4)        -> 800256
// off     @ 800256    ((N+1)*4 pad)-> 1200384
// bsum    @ 1200384   (512)        -> 1200896
// cursor  @ 1200896   (N*4)        -> 1600896
// stats   @ 1600896   (3*128 f32)  -> 1602432
// c0      @ 1602432   (64 f32)     -> 1602688
// Weff    @ 1602688   (4096 f32)   -> 1619072
// ceff    @ 1619072   (64 f32)     -> 1619328 (pad -> 1619456)
// packed  @ 1619456   (E*8)        -> 14419456
// h       @ 14419456  (N*64*4)     -> 40019456
// agg     @ 40019456  (N*64*4)     -> 65619456   (~65.6 MB total)

#define SCAN_BLOCKS 128
#define SCAN_T 256

// Zero deg/stats/c0; last block detects int64-vs-int32 edge_index layout
// (odd 32-bit words all-zero => int64 high halves => flag=1).
__global__ void setup_kernel(const unsigned* __restrict__ ei, int* __restrict__ flag,
                             int* __restrict__ deg, float* __restrict__ stats,
                             float* __restrict__ c0) {
    int t = blockIdx.x * 256 + threadIdx.x;
    if (t < N_NODES) deg[t] = 0;
    if (t < 384) stats[t] = 0.f;
    if (t < 64) c0[t] = 0.f;
    if (blockIdx.x == gridDim.x - 1) {
        int tt = threadIdx.x;
        unsigned stride = (2u * (unsigned)N_EDGES) / 256u;  // even
        unsigned v = ei[(unsigned)tt * stride + 1u];        // odd word
        __shared__ unsigned red[256];
        red[tt] = v;
        __syncthreads();
        for (int s = 128; s > 0; s >>= 1) {
            if (tt < s) red[tt] |= red[tt + s];
            __syncthreads();
        }
        if (tt == 0) *flag = (red[0] == 0u) ? 1 : 0;
    }
}

// 2 edges per thread, vectorized index loads.
__global__ void degcount_kernel(const void* __restrict__ ei, const int* __restrict__ flag,
                                int* __restrict__ deg) {
    int t = blockIdx.x * 256 + threadIdx.x;
    if (t >= N_EDGES / 2) return;
    int d0, d1;
    if (*flag) {
        const longlong2* dp = (const longlong2*)((const long long*)ei + N_EDGES);
        longlong2 d = dp[t];
        d0 = (int)d.x; d1 = (int)d.y;
    } else {
        const int2* dp = (const int2*)((const int*)ei + N_EDGES);
        int2 d = dp[t];
        d0 = d.x; d1 = d.y;
    }
    atomicAdd(&deg[d0], 1);
    atomicAdd(&deg[d1], 1);
}

// Per-block degree sums for the scan + dinv = rsqrt(deg+1) fused in.
__global__ void scanA_kernel(const int* __restrict__ deg, float* __restrict__ dinv,
                             int* __restrict__ bsum) {
    int b = blockIdx.x, t = threadIdx.x;
    const int chunk = (N_NODES + SCAN_BLOCKS - 1) / SCAN_BLOCKS;  // 782
    const int tchunk = (chunk + SCAN_T - 1) / SCAN_T;             // 4
    int lo = b * chunk + t * tchunk;
    int hi = min(lo + tchunk, min((b + 1) * chunk, N_NODES));
    int s = 0;
    for (int i = lo; i < hi; ++i) {
        int d = deg[i];
        s += d;
        dinv[i] = rsqrtf((float)d + 1.0f);
    }
    __shared__ int red[SCAN_T];
    red[t] = s;
    __syncthreads();
    for (int st = 128; st > 0; st >>= 1) {
        if (t < st) red[t] += red[t + st];
        __syncthreads();
    }
    if (t == 0) bsum[b] = red[0];
}

__global__ void scanB_kernel(int* __restrict__ bsum) {
    __shared__ int sh[SCAN_BLOCKS];
    int t = threadIdx.x;
    sh[t] = bsum[t];
    __syncthreads();
    for (int st = 1; st < SCAN_BLOCKS; st <<= 1) {
        int v = (t >= st) ? sh[t - st] : 0;
        __syncthreads();
        sh[t] += v;
        __syncthreads();
    }
    bsum[t] = (t == 0) ? 0 : sh[t - 1];  // exclusive
}

__global__ void scanC_kernel(const int* __restrict__ deg, const int* __restrict__ bsum,
                             int* __restrict__ off, int* __restrict__ cursor) {
    int b = blockIdx.x, t = threadIdx.x;
    const int chunk = (N_NODES + SCAN_BLOCKS - 1) / SCAN_BLOCKS;
    const int tchunk = (chunk + SCAN_T - 1) / SCAN_T;
    int lo = b * chunk + t * tchunk;
    int hi = min(lo + tchunk, min((b + 1) * chunk, N_NODES));
    int s = 0;
    for (int i = lo; i < hi; ++i) s += deg[i];
    __shared__ int red[SCAN_T];
    red[t] = s;
    __syncthreads();
    for (int st = 1; st < SCAN_T; st <<= 1) {
        int v = (t >= st) ? red[t - st] : 0;
        __syncthreads();
        red[t] += v;
        __syncthreads();
    }
    int tbase = bsum[b] + red[t] - s;  // exclusive prefix for this thread
    for (int i = lo; i < hi; ++i) {
        int d = deg[i];
        off[i] = tbase;
        cursor[i] = tbase;
        tbase += d;
    }
    if (b == 0 && t == 0) off[N_NODES] = N_EDGES;
}

// 2 edges per thread; pack {src, dinv[src]} into 8B at CSR position.
__global__ void bucket_kernel(const void* __restrict__ ei, const int* __restrict__ flag,
                              const float* __restrict__ dinv, int* __restrict__ cursor,
                              long long* __restrict__ packed) {
    int t = blockIdx.x * 256 + threadIdx.x;
    if (t >= N_EDGES / 2) return;
    int s0, s1, d0, d1;
    if (*flag) {
        const longlong2* sp = (const longlong2*)ei;
        const longlong2* dp = (const longlong2*)((const long long*)ei + N_EDGES);
        longlong2 s = sp[t], d = dp[t];
        s0 = (int)s.x; s1 = (int)s.y; d0 = (int)d.x; d1 = (int)d.y;
    } else {
        const int2* sp = (const int2*)ei;
        const int2* dp = (const int2*)((const int*)ei + N_EDGES);
        int2 s = sp[t], d = dp[t];
        s0 = s.x; s1 = s.y; d0 = d.x; d1 = d.y;
    }
    int p0 = atomicAdd(&cursor[d0], 1);
    int p1 = atomicAdd(&cursor[d1], 1);
    unsigned long long pk0 = (unsigned long long)(unsigned)s0 |
                             ((unsigned long long)__float_as_uint(dinv[s0]) << 32);
    unsigned long long pk1 = (unsigned long long)(unsigned)s1 |
                             ((unsigned long long)__float_as_uint(dinv[s1]) << 32);
    __builtin_nontemporal_store((long long)pk0, &packed[p0]);
    __builtin_nontemporal_store((long long)pk1, &packed[p1]);
}

// h = x @ W + c.  One wave per row: lane = output column, W column in 64 VGPRs,
// x-row reads wave-uniform (broadcast), float4-vectorized, 4 split accumulators.
__global__ __launch_bounds__(256) void gemm_kernel(const float* __restrict__ x,
                                                   const float* __restrict__ W,
                                                   const float* __restrict__ c,
                                                   float* __restrict__ h) {
    int lane = threadIdx.x & 63;
    int wv = threadIdx.x >> 6;
    float wcol[64];
#pragma unroll
    for (int k = 0; k < 64; ++k) wcol[k] = W[k * 64 + lane];
    float bias = c[lane];
    int row0 = blockIdx.x * 64;
    for (int r = wv; r < 64; r += 4) {
        int row = row0 + r;
        if (row >= N_NODES) break;
        const float4* xr = reinterpret_cast<const float4*>(x + (size_t)row * 64);
        float a0 = 0.f, a1 = 0.f, a2 = 0.f, a3 = 0.f;
#pragma unroll
        for (int k4 = 0; k4 < 16; ++k4) {
            float4 xv = xr[k4];
            a0 += xv.x * wcol[4 * k4 + 0];
            a1 += xv.y * wcol[4 * k4 + 1];
            a2 += xv.z * wcol[4 * k4 + 2];
            a3 += xv.w * wcol[4 * k4 + 3];
        }
        h[(size_t)row * 64 + lane] = (a0 + a1) + (a2 + a3) + bias;
    }
}

// agg[n] = relu( dinv[n]^2*h[n] + b + sum_{e:dst=n} dinv[src]*dinv[n]*h[src] )
// Wave per node; 4 lane-groups x 2-deep unroll = 8 h-rows in flight per wave.
__global__ __launch_bounds__(256) void gather_kernel(const float* __restrict__ h,
                                                     const int* __restrict__ off,
                                                     const long long* __restrict__ packed,
                                                     const float* __restrict__ dinv,
                                                     const float* __restrict__ b,
                                                     float* __restrict__ agg) {
    int lane = threadIdx.x & 63;
    int wv = threadIdx.x >> 6;
    int n = blockIdx.x * 4 + wv;
    if (n >= N_NODES) return;
    int g = lane >> 4;    // edge sub-group 0..3
    int fq = lane & 15;   // feature quad
    const float4* h4 = reinterpret_cast<const float4*>(h);
    float dn = dinv[n];
    float4 acc0 = make_float4(0.f, 0.f, 0.f, 0.f);
    float4 acc1 = make_float4(0.f, 0.f, 0.f, 0.f);
    int j0 = off[n], j1 = off[n + 1];
    int j = j0;
    for (; j + 8 <= j1; j += 8) {
        long long pk0 = packed[j + g];
        long long pk1 = packed[j + 4 + g];
        int s0 = (int)(pk0 & 0xffffffffLL);
        int s1 = (int)(pk1 & 0xffffffffLL);
        float w0 = __int_as_float((int)(pk0 >> 32)) * dn;
        float w1 = __int_as_float((int)(pk1 >> 32)) * dn;
        float4 h0 = h4[s0 * 16 + fq];
        float4 h1 = h4[s1 * 16 + fq];
        acc0.x += w0 * h0.x; acc0.y += w0 * h0.y; acc0.z += w0 * h0.z; acc0.w += w0 * h0.w;
        acc1.x += w1 * h1.x; acc1.y += w1 * h1.y; acc1.z += w1 * h1.z; acc1.w += w1 * h1.w;
    }
    for (; j < j1; j += 4) {
        int jj = j + g;
        if (jj < j1) {
            long long pk = packed[jj];
            int s = (int)(pk & 0xffffffffLL);
            float w = __int_as_float((int)(pk >> 32)) * dn;
            float4 hv = h4[s * 16 + fq];
            acc0.x += w * hv.x; acc0.y += w * hv.y; acc0.z += w * hv.z; acc0.w += w * hv.w;
        }
    }
    acc0.x += acc1.x; acc0.y += acc1.y; acc0.z += acc1.z; acc0.w += acc1.w;
#pragma unroll
    for (int m = 16; m <= 32; m <<= 1) {
        acc0.x += __shfl_xor(acc0.x, m, 64);
        acc0.y += __shfl_xor(acc0.y, m, 64);
        acc0.z += __shfl_xor(acc0.z, m, 64);
        acc0.w += __shfl_xor(acc0.w, m, 64);
    }
    if (g == 0) {
        float4 hv = h4[n * 16 + fq];
        float4 bv = reinterpret_cast<const float4*>(b)[fq];
        float sw = dn * dn;
        float4 o;
        o.x = fmaxf(acc0.x + sw * hv.x + bv.x, 0.f);
        o.y = fmaxf(acc0.y + sw * hv.y + bv.y, 0.f);
        o.z = fmaxf(acc0.z + sw * hv.z + bv.z, 0.f);
        o.w = fmaxf(acc0.w + sw * hv.w + bv.w, 0.f);
        reinterpret_cast<float4*>(agg + (size_t)n * 64)[fq] = o;
    }
}

// Column sums / sum-of-squares of agg (already relu'd) -> stats[0:64],[64:128].
__global__ __launch_bounds__(256) void stats_kernel(const float* __restrict__ agg,
                                                    float* __restrict__ stats) {
    int lane = threadIdx.x & 63;
    int sub = threadIdx.x >> 6;
    int fq = lane & 15, rs = lane >> 4;
    const float4* a4 = reinterpret_cast<const float4*>(agg);
    float4 s1 = make_float4(0.f, 0.f, 0.f, 0.f);
    float4 s2 = make_float4(0.f, 0.f, 0.f, 0.f);
    // each wave covers 4 rows (1KB) per iteration
    for (int r4 = blockIdx.x * 4 + sub; r4 < N_NODES / 4; r4 += gridDim.x * 4) {
        float4 v = a4[(size_t)(r4 * 4 + rs) * 16 + fq];
        s1.x += v.x; s1.y += v.y; s1.z += v.z; s1.w += v.w;
        s2.x += v.x * v.x; s2.y += v.y * v.y; s2.z += v.z * v.z; s2.w += v.w * v.w;
    }
#pragma unroll
    for (int m = 16; m <= 32; m <<= 1) {
        s1.x += __shfl_xor(s1.x, m, 64); s1.y += __shfl_xor(s1.y, m, 64);
        s1.z += __shfl_xor(s1.z, m, 64); s1.w += __shfl_xor(s1.w, m, 64);
        s2.x += __shfl_xor(s2.x, m, 64); s2.y += __shfl_xor(s2.y, m, 64);
        s2.z += __shfl_xor(s2.z, m, 64); s2.w += __shfl_xor(s2.w, m, 64);
    }
    __shared__ float red[4][128];
    if (rs == 0) {
        reinterpret_cast<float4*>(&red[sub][0])[fq] = s1;
        reinterpret_cast<float4*>(&red[sub][64])[fq] = s2;
    }
    __syncthreads();
    int t = threadIdx.x;
    if (t < 128) {
        float v = red[0][t] + red[1][t] + red[2][t] + red[3][t];
        atomicAdd(&stats[t], v);
    }
}

// Fold BN(l-1) into W(l):  Weff = diag(gamma*rs) W,  ceff = (beta - scale*mean)^T W
__global__ void prep_kernel(const float* __restrict__ stats, const float* __restrict__ gamma,
                            const float* __restrict__ beta, const float* __restrict__ W,
                            float* __restrict__ Weff, float* __restrict__ ceff) {
    __shared__ float s_scale[64], s_shift[64];
    int t = threadIdx.x;
    if (t < 64) {
        const float invN = 1.0f / (float)N_NODES;
        float mean = stats[t] * invN;
        float var = stats[64 + t] * invN - mean * mean;
        float rs = rsqrtf(var + EPS);
        float sc = gamma[t] * rs;
        s_scale[t] = sc;
        s_shift[t] = beta[t] - sc * mean;
    }
    __syncthreads();
    for (int idx = t; idx < 4096; idx += 256) Weff[idx] = s_scale[idx >> 6] * W[idx];
    if (t < 64) {
        float c = 0.f;
        for (int k = 0; k < 64; ++k) c += s_shift[k] * W[k * 64 + t];
        ceff[t] = c;
    }
}

// Final BN for the output layer (agg already relu'd).
__global__ __launch_bounds__(256) void apply_kernel(const float* __restrict__ agg,
                                                    const float* __restrict__ stats,
                                                    const float* __restrict__ gamma,
                                                    const float* __restrict__ beta,
                                                    float* __restrict__ out) {
    int i = blockIdx.x * 256 + threadIdx.x;
    if (i >= N_NODES * 16) return;
    int d0 = (i & 15) << 2;
    float4 v = reinterpret_cast<const float4*>(agg)[i];
    float r[4] = {v.x, v.y, v.z, v.w};
    float4 o;
    float* op = &o.x;
    const float invN = 1.0f / (float)N_NODES;
#pragma unroll
    for (int j = 0; j < 4; ++j) {
        int d = d0 + j;
        float mean = stats[d] * invN;
        float var = stats[64 + d] * invN - mean * mean;
        float rs = rsqrtf(var + EPS);
        op[j] = gamma[d] * (r[j] - mean) * rs + beta[d];
    }
    reinterpret_cast<float4*>(out)[i] = o;
}

extern "C" void kernel_launch(void* const* d_in, const int* in_sizes, int n_in,
                              void* d_out, int out_size, void* d_ws, size_t ws_size,
                              hipStream_t stream) {
    const void* ei = d_in[0];
    const float* node_attr = (const float*)d_in[1];
    // d_in[2] = edge_attr (unused by the reference)

    char* ws = (char*)d_ws;
    int* flag = (int*)(ws + 0);
    int* deg = (int*)(ws + 256);
    float* dinv = (float*)(ws + 400256);
    int* off = (int*)(ws + 800256);
    int* bsum = (int*)(ws + 1200384);
    int* cursor = (int*)(ws + 1200896);
    float* stats = (float*)(ws + 1600896);
    float* c0 = (float*)(ws + 1602432);
    float* Weff = (float*)(ws + 1602688);
    float* ceff = (float*)(ws + 1619072);
    long long* packed = (long long*)(ws + 1619456);
    float* h = (float*)(ws + 14419456);
    float* agg = (float*)(ws + 40019456);

    setup_kernel<<<(N_NODES + 255) / 256, 256, 0, stream>>>((const unsigned*)ei, flag, deg,
                                                            stats, c0);
    degcount_kernel<<<(N_EDGES / 2 + 255) / 256, 256, 0, stream>>>(ei, flag, deg);
    scanA_kernel<<<SCAN_BLOCKS, SCAN_T, 0, stream>>>(deg, dinv, bsum);
    scanB_kernel<<<1, SCAN_BLOCKS, 0, stream>>>(bsum);
    scanC_kernel<<<SCAN_BLOCKS, SCAN_T, 0, stream>>>(deg, bsum, off, cursor);
    bucket_kernel<<<(N_EDGES / 2 + 255) / 256, 256, 0, stream>>>(ei, flag, dinv, cursor, packed);

    const float* x = node_attr;
    for (int l = 0; l < 3; ++l) {
        const float* W = (const float*)d_in[3 + 4 * l];
        const float* b = (const float*)d_in[4 + 4 * l];
        float* stats_l = stats + 128 * l;

        const float* Wuse;
        const float* cuse;
        if (l == 0) {
            Wuse = W;
            cuse = c0;
        } else {
            // fold BN of layer l-1 into this layer's weights
            const float* gamma_p = (const float*)d_in[5 + 4 * (l - 1)];
            const float* beta_p = (const float*)d_in[6 + 4 * (l - 1)];
            prep_kernel<<<1, 256, 0, stream>>>(stats + 128 * (l - 1), gamma_p, beta_p, W,
                                               Weff, ceff);
            Wuse = Weff;
            cuse = ceff;
        }

        gemm_kernel<<<(N_NODES + 63) / 64, 256, 0, stream>>>(x, Wuse, cuse, h);
        gather_kernel<<<(N_NODES + 3) / 4, 256, 0, stream>>>(h, off, packed, dinv, b, agg);
        stats_kernel<<<1024, 256, 0, stream>>>(agg, stats_l);
        x = agg;
    }
    const float* gamma3 = (const float*)d_in[5 + 4 * 2];
    const float* beta3 = (const float*)d_in[6 + 4 * 2];
    apply_kernel<<<(N_NODES * 16 + 255) / 256, 256, 0, stream>>>(agg, stats + 256, gamma3,
                                                                 beta3, (float*)d_out);
}